// Round 15
// baseline (191.563 us; speedup 1.0000x reference)
//
#include <hip/hip_runtime.h>
#include <math.h>

typedef float  f32x4   __attribute__((ext_vector_type(4)));
typedef float  f32x16  __attribute__((ext_vector_type(16)));
typedef __bf16 bf16x8  __attribute__((ext_vector_type(8)));
typedef __bf16 bf16x4  __attribute__((ext_vector_type(4)));

#define MFMA16(a, b, c) __builtin_amdgcn_mfma_f32_16x16x32_bf16((a), (b), (c), 0, 0, 0)
#define MFMA32(a, b, c) __builtin_amdgcn_mfma_f32_32x32x16_bf16((a), (b), (c), 0, 0, 0)

typedef __attribute__((address_space(3))) unsigned int lds_u32;
typedef __attribute__((address_space(1))) const unsigned int glb_u32;

__device__ __forceinline__ void gload16(const __bf16* g, char* l) {
    __builtin_amdgcn_global_load_lds((glb_u32*)g, (lds_u32*)l, 16, 0, 0);
}

// problem sizes
static constexpr int BATCH = 4;
static constexpr int CH    = 256;
static constexpr int M_TOT = BATCH * 4096;  // 16384

// qkv softmax pre-scale folded into Q: 0.125 * log2(e)
static constexpr float QSCALE = 0.18033688011112042f;

// workspace layout (bytes, 16-aligned)
static constexpr size_t OFF_WQKV  = 0;                              // 196608 bf16
static constexpr size_t OFF_WOUT  = 196608ull * 2;                  // 65536 bf16
static constexpr size_t OFF_STATS = OFF_WOUT + 65536ull * 2;        // 128 float2
static constexpr size_t OFF_HID   = OFF_STATS + 1024;               // hid / attn_out bf16
static constexpr size_t OFF_Q     = OFF_HID + (size_t)M_TOT * CH * 2;
static constexpr size_t OFF_K     = OFF_Q   + (size_t)M_TOT * CH * 2;
static constexpr size_t OFF_V     = OFF_K   + (size_t)M_TOT * CH * 2;  // V^T [16][64][4096]

// ---------------------------------------------------------------------------
// 1) fused: GN stats (blocks 0..127) + weight convert/permute (blocks 128..1151)
// ---------------------------------------------------------------------------
__global__ __launch_bounds__(256) void pre_kernel(const float* __restrict__ x,
                                                  float2* __restrict__ stats,
                                                  const float* __restrict__ wq,
                                                  const float* __restrict__ wo,
                                                  __bf16* __restrict__ wqf,
                                                  __bf16* __restrict__ wof) {
    if (blockIdx.x < 128) {
        int bg = blockIdx.x;  // 0..127
        const float4* p = (const float4*)(x + (size_t)bg * 32768);
        float s = 0.f, ss = 0.f;
        for (int i = threadIdx.x; i < 8192; i += 256) {
            float4 v = p[i];
            s  += (v.x + v.y) + (v.z + v.w);
            ss += v.x * v.x + v.y * v.y + v.z * v.z + v.w * v.w;
        }
#pragma unroll
        for (int d = 32; d > 0; d >>= 1) { s += __shfl_down(s, d); ss += __shfl_down(ss, d); }
        __shared__ float sh[8];
        int w = threadIdx.x >> 6, l = threadIdx.x & 63;
        if (l == 0) { sh[w] = s; sh[4 + w] = ss; }
        __syncthreads();
        if (threadIdx.x == 0) {
            float S = sh[0] + sh[1] + sh[2] + sh[3];
            float SS = sh[4] + sh[5] + sh[6] + sh[7];
            float mean = S * (1.f / 32768.f);
            float var  = SS * (1.f / 32768.f) - mean * mean;
            stats[bg] = make_float2(mean, rsqrtf(var + 1e-5f));
        }
    } else {
        int i = (blockIdx.x - 128) * 256 + threadIdx.x;   // 0 .. 262143
        if (i < 196608) {
            int e = i & 7, l = (i >> 3) & 63, kk = (i >> 9) & 7, jt = i >> 12;  // jt 0..47
            int kidx = kk * 32 + ((l >> 4) << 3) + e;
            int n = jt * 16 + (l & 15);
            wqf[i] = (__bf16)wq[kidx * 768 + n];
        } else {
            int i2 = i - 196608;                  // 0 .. 65535
            int e = i2 & 7, l = (i2 >> 3) & 63, kk = (i2 >> 9) & 7, jt = i2 >> 12;  // jt 0..15
            int kidx = kk * 32 + ((l >> 4) << 3) + e;
            int n = jt * 16 + (l & 15);
            wof[i2] = (__bf16)wo[kidx * 256 + n];
        }
    }
}

// ---------------------------------------------------------------------------
// 2) GN apply + transpose: hid[b][n][c] = gn(x)[b][c][n]  (bf16)
// ---------------------------------------------------------------------------
__global__ __launch_bounds__(256) void gn_apply(const float* __restrict__ x,
                                                const float* __restrict__ gamma,
                                                const float* __restrict__ beta,
                                                const float2* __restrict__ stats,
                                                __bf16* __restrict__ hid) {
    int b  = blockIdx.x >> 6;
    int n0 = (blockIdx.x & 63) << 6;
    int c  = threadIdx.x;
    float2 st = stats[b * 32 + (c >> 3)];
    float gm = gamma[c] * st.y;
    float bt = beta[c] - st.x * gm;
    const float* xp = x + ((size_t)(b * 256 + c)) * 4096 + n0;
    __bf16* hp = hid + ((size_t)(b * 4096 + n0)) * 256 + c;
#pragma unroll
    for (int j4 = 0; j4 < 16; ++j4) {
        float4 v = *(const float4*)(xp + j4 * 4);
        hp[(size_t)(j4 * 4 + 0) * 256] = (__bf16)(v.x * gm + bt);
        hp[(size_t)(j4 * 4 + 1) * 256] = (__bf16)(v.y * gm + bt);
        hp[(size_t)(j4 * 4 + 2) * 256] = (__bf16)(v.z * gm + bt);
        hp[(size_t)(j4 * 4 + 3) * 256] = (__bf16)(v.w * gm + bt);
    }
}

// ---------------------------------------------------------------------------
// 3) QKV GEMM: [16384,256] x [256,768] + bias.
//    q,k -> [B,H,4096,64];  v -> V^T [B*H, 64, 4096] with kappa column order
//    via LDS-transpose epilogue. Q pre-scaled by 0.125*log2(e).
// ---------------------------------------------------------------------------
__global__ __launch_bounds__(256) void qkv_gemm(const __bf16* __restrict__ hid,
                                                const __bf16* __restrict__ wf,
                                                const float* __restrict__ bqkv,
                                                __bf16* __restrict__ qb,
                                                __bf16* __restrict__ kb,
                                                __bf16* __restrict__ vb) {
    const int mt = blockIdx.x, nt = blockIdx.y;
    const int tid = threadIdx.x;
    const int w = tid >> 6, l = tid & 63;
    const int lr = l & 15, lh = l >> 4;
    f32x4 acc[4] = {{0.f,0.f,0.f,0.f},{0.f,0.f,0.f,0.f},{0.f,0.f,0.f,0.f},{0.f,0.f,0.f,0.f}};
    const __bf16* ap = hid + (size_t)(mt * 64 + w * 16 + lr) * 256 + lh * 8;
#pragma unroll
    for (int kk = 0; kk < 8; ++kk) {
        bf16x8 a = *(const bf16x8*)(ap + kk * 32);
#pragma unroll
        for (int fj = 0; fj < 4; ++fj) {
            bf16x8 bf = *(const bf16x8*)(wf + (size_t)(((nt * 4 + fj) * 8 + kk) * 64 + l) * 8);
            acc[fj] = MFMA16(a, bf, acc[fj]);
        }
    }
    const int part = nt % 3;           // 0=q 1=k 2=v (uniform per block)
    const int head = nt / 3;
    const int b  = mt >> 6;
    const int n0 = (mt & 63) * 64;

    if (part == 2) {
        // V block: route through LDS transpose, store V^T with kappa col order
        __shared__ float tile[64][72];
#pragma unroll
        for (int fj = 0; fj < 4; ++fj) {
            float bias = bqkv[head * 192 + 128 + fj * 16 + lr];
#pragma unroll
            for (int r = 0; r < 4; ++r)
                tile[w * 16 + lh * 4 + r][fj * 16 + lr] = acc[fj][r] + bias;
        }
        __syncthreads();
        int dd = tid >> 2, nq = tid & 3;
        __bf16* dstrow = vb + ((size_t)((b * 4 + head) * 64 + dd)) * 4096 + n0 + nq * 16;
        bf16x8 w0, w1;
#pragma unroll
        for (int cc = 0; cc < 8; ++cc) {
            int nl0 = nq * 16 + 8 * ((cc >> 2) & 1) + 4 * (cc >> 3) + (cc & 3);
            int cc1 = cc + 8;
            int nl1 = nq * 16 + 8 * ((cc1 >> 2) & 1) + 4 * (cc1 >> 3) + (cc1 & 3);
            w0[cc] = (__bf16)tile[nl0][dd];
            w1[cc] = (__bf16)tile[nl1][dd];
        }
        *(bf16x8*)dstrow = w0;
        *(bf16x8*)(dstrow + 8) = w1;
    } else {
        __bf16* dst = (part == 0) ? qb : kb;
        const float sc = (part == 0) ? QSCALE : 1.0f;
        int mbase = w * 16 + lh * 4;
#pragma unroll
        for (int fj = 0; fj < 4; ++fj) {
            int dd = fj * 16 + lr;
            float bias = bqkv[head * 192 + part * 64 + dd];
#pragma unroll
            for (int r = 0; r < 4; ++r) {
                int n = n0 + mbase + r;
                dst[((size_t)((b * 4 + head) * 4096 + n)) * 64 + dd] = (__bf16)((acc[fj][r] + bias) * sc);
            }
        }
    }
}

// ---------------------------------------------------------------------------
// 4) Flash attention, split-K: grid 1024 (XCD swizzle), 4 waves/block.
//    Block owns 64 q-rows; wave pair 0 handles keys [0,2048), pair 1 handles
//    [2048,4096) (static softmax -> partials combine by pure addition).
//    32-key tiles, 32x32x16 MFMAs, fragment-major LDS (conflict-free),
//    V^T-in-global kappa-ordered; lsum = scalar f32 adds (no ones-MFMA).
//    LDS 32KB/block -> 4 blocks/CU = 4 waves/SIMD.
// ---------------------------------------------------------------------------
__global__ __launch_bounds__(256, 4) void attn_fwd(const __bf16* __restrict__ q,
                                                   const __bf16* __restrict__ k,
                                                   const __bf16* __restrict__ vt,
                                                   __bf16* __restrict__ ao) {
    const int id = blockIdx.x;                        // 0..1023
    const int within = id >> 3;                       // 0..127
    const int bh = ((id & 7) << 1) + (within >> 6);   // XCD (id&7) owns bh pair
    const int q0 = (within & 63) * 64;
    const int tid = threadIdx.x;
    const int wv = tid >> 6, l = tid & 63;
    const int l31 = l & 31, h = l >> 5;
    const int pair = wv >> 1;          // key half
    const int wq   = wv & 1;           // wave-in-pair == q-subtile

    __shared__ __attribute__((aligned(16))) char smem[32768];  // 2 pairs x (K dbuf 8K | V dbuf 8K)

    const size_t base = (size_t)bh * (4096 * 64);
    const __bf16* kg = k + base;
    const __bf16* vg = vt + base;      // V^T [64][4096]

    // ---- staging constants (per thread; pair-local tiles of 32 keys) ----
    // K frag f=r*2+wq: lane ll holds K[key=(ll&31)][d = f*16 + (ll>>5)*8 + e]
    const int kS0 = (l & 31) * 64 + wq * 16 + (l >> 5) * 8;     // r=0 (frag wq)
    const int kS1 = kS0 + 32;                                    // r=1 (frag 2+wq)
    // V frag f=r*2+wq: lane ll holds V^T[d = r*32+(ll&31)][col = wq*16 + (ll>>5)*8 + e]
    const int vS0 = (l & 31) * 4096 + wq * 16 + (l >> 5) * 8;   // r=0 (d32=0)
    const int vS1 = vS0 + 32 * 4096;                             // r=1 (d32=1)
    const int dst0 = wq * 1024 + l * 16;                         // frag wq
    const int dst1 = dst0 + 2048;                                // frag 2+wq
    const int pairBase = pair * 16384;
    const int kTileStride = 2048;                                // 32 keys * 64 d elems
    const int pairKeyElemsK = pair * 131072;                     // 2048 keys * 64
    const int pairColV = pair * 2048;                            // column offset in V^T

    // Q B-frags: lane holds Q[q = q0 + wq*32 + l31][ks*16 + h*8 + e]
    bf16x8 qf[4];
    {
        const __bf16* qp = q + base + (size_t)(q0 + wq * 32 + l31) * 64 + h * 8;
#pragma unroll
        for (int ks = 0; ks < 4; ++ks) qf[ks] = *(const bf16x8*)(qp + ks * 16);
    }

    f32x16 O0 = (f32x16)0.0f, O1 = (f32x16)0.0f;
    float ls = 0.f;

    // prologue: stage tile 0 (both pairs) into buf 0
    gload16(kg + pairKeyElemsK + kS0, smem + pairBase + dst0);
    gload16(kg + pairKeyElemsK + kS1, smem + pairBase + dst1);
    gload16(vg + pairColV + vS0, smem + pairBase + 8192 + dst0);
    gload16(vg + pairColV + vS1, smem + pairBase + 8192 + dst1);
    __syncthreads();

    auto body = [&](int buf, int tnext) {
        if (tnext < 64) {
            const __bf16* kp = kg + pairKeyElemsK + tnext * kTileStride;
            const __bf16* vp = vg + pairColV + tnext * 32;
            char* kd = smem + pairBase + (buf ^ 1) * 4096;
            char* vd = smem + pairBase + 8192 + (buf ^ 1) * 4096;
            gload16(kp + kS0, kd + dst0);
            gload16(kp + kS1, kd + dst1);
            gload16(vp + vS0, vd + dst0);
            gload16(vp + vS1, vd + dst1);
        }
        const char* Kl = smem + pairBase + buf * 4096 + l * 16;
        const char* Vl = smem + pairBase + 8192 + buf * 4096 + l * 16;

        // ---- S^T = K Q^T (4 chained MFMA32 over d) ----
        f32x16 S = (f32x16)0.0f;
        __builtin_amdgcn_s_setprio(1);
#pragma unroll
        for (int ks = 0; ks < 4; ++ks)
            S = MFMA32(*(const bf16x8*)(Kl + ks * 1024), qf[ks], S);
        __builtin_amdgcn_s_setprio(0);

        // ---- static softmax: p = exp2(S); scalar lsum; B-frags identity ----
        bf16x8 B0, B1;
#pragma unroll
        for (int e = 0; e < 8; ++e) {
            float p0 = __builtin_amdgcn_exp2f(S[e]);
            float p1 = __builtin_amdgcn_exp2f(S[8 + e]);
            ls += p0 + p1;
            B0[e] = (__bf16)p0;
            B1[e] = (__bf16)p1;
        }

        // ---- O^T += V^T P (4 MFMA32) ----
        __builtin_amdgcn_s_setprio(1);
        O0 = MFMA32(*(const bf16x8*)(Vl + 0),    B0, O0);
        O0 = MFMA32(*(const bf16x8*)(Vl + 1024), B1, O0);
        O1 = MFMA32(*(const bf16x8*)(Vl + 2048), B0, O1);
        O1 = MFMA32(*(const bf16x8*)(Vl + 3072), B1, O1);
        __builtin_amdgcn_s_setprio(0);

        __syncthreads();   // implicit vmcnt(0): staging landed; buf flip safe
    };

    for (int t = 0; t < 64; t += 2) {
        body(0, t + 1);
        body(1, t + 2);
    }

    // ---- split-K combine: pair 1 writes partials; pair 0 reduces + stores ----
    if (wv >= 2) {
        float* d = (float*)(smem + ((wv - 2) * 64 + l) * 144);
        const f32x4* o0p = (const f32x4*)&O0;
        const f32x4* o1p = (const f32x4*)&O1;
#pragma unroll
        for (int i = 0; i < 4; ++i) ((f32x4*)d)[i] = o0p[i];
#pragma unroll
        for (int i = 0; i < 4; ++i) ((f32x4*)(d + 16))[i] = o1p[i];
        d[32] = ls;
    }
    __syncthreads();
    if (wv < 2) {
        const float* s = (const float*)(smem + (wv * 64 + l) * 144);
#pragma unroll
        for (int j = 0; j < 16; ++j) { O0[j] += s[j]; O1[j] += s[16 + j]; }
        ls += s[32];
        ls += __shfl_xor(ls, 32);
        float inv = 1.0f / ls;
        int b = bh >> 2, hd = bh & 3;
        int n = q0 + wv * 32 + l31;
        __bf16* dst = ao + ((size_t)(b * 4096 + n)) * 256 + hd * 64 + h * 4;
#pragma unroll
        for (int dt = 0; dt < 2; ++dt) {
            const f32x16& O = dt ? O1 : O0;
#pragma unroll
            for (int g = 0; g < 4; ++g) {
                bf16x4 pk;
#pragma unroll
                for (int m = 0; m < 4; ++m) pk[m] = (__bf16)(O[g * 4 + m] * inv);
                *(bf16x4*)(dst + dt * 32 + g * 8) = pk;
            }
        }
    }
}

// ---------------------------------------------------------------------------
// 5) out projection + bias + residual + 1/sqrt(2), transposed store [B,C,N]
// ---------------------------------------------------------------------------
__global__ __launch_bounds__(256) void out_gemm(const __bf16* __restrict__ ao,
                                                const __bf16* __restrict__ wf,
                                                const float* __restrict__ bout,
                                                const float* __restrict__ x,
                                                float* __restrict__ out) {
    const int mt = blockIdx.x, nt = blockIdx.y;
    const int tid = threadIdx.x;
    const int w = tid >> 6, l = tid & 63;
    const int lr = l & 15, lh = l >> 4;
    f32x4 acc[4] = {{0.f,0.f,0.f,0.f},{0.f,0.f,0.f,0.f},{0.f,0.f,0.f,0.f},{0.f,0.f,0.f,0.f}};
    const __bf16* ap = ao + (size_t)(mt * 64 + w * 16 + lr) * 256 + lh * 8;
#pragma unroll
    for (int kk = 0; kk < 8; ++kk) {
        bf16x8 a = *(const bf16x8*)(ap + kk * 32);
#pragma unroll
        for (int fj = 0; fj < 4; ++fj) {
            bf16x8 bf = *(const bf16x8*)(wf + (size_t)(((nt * 4 + fj) * 8 + kk) * 64 + l) * 8);
            acc[fj] = MFMA16(a, bf, acc[fj]);
        }
    }
    __shared__ float tile[64][72];
#pragma unroll
    for (int fj = 0; fj < 4; ++fj) {
        float bias = bout[nt * 64 + fj * 16 + lr];
#pragma unroll
        for (int r = 0; r < 4; ++r)
            tile[w * 16 + lh * 4 + r][fj * 16 + lr] = acc[fj][r] + bias;
    }
    __syncthreads();
    int b  = mt >> 6;
    int n0 = (mt & 63) * 64;
    int c0 = nt * 64;
    int cl = tid >> 2, nq = tid & 3;
    size_t gbase = ((size_t)(b * 256 + c0 + cl)) * 4096 + n0 + nq * 16;
#pragma unroll
    for (int i = 0; i < 16; i += 4) {
        float4 xv = *(const float4*)(x + gbase + i);
        float4 ov;
        ov.x = (tile[nq * 16 + i + 0][cl] + xv.x) * 0.70710678118654752f;
        ov.y = (tile[nq * 16 + i + 1][cl] + xv.y) * 0.70710678118654752f;
        ov.z = (tile[nq * 16 + i + 2][cl] + xv.z) * 0.70710678118654752f;
        ov.w = (tile[nq * 16 + i + 3][cl] + xv.w) * 0.70710678118654752f;
        *(float4*)(out + gbase + i) = ov;
    }
}

// ---------------------------------------------------------------------------
extern "C" void kernel_launch(void* const* d_in, const int* in_sizes, int n_in,
                              void* d_out, int out_size, void* d_ws, size_t ws_size,
                              hipStream_t stream) {
    const float* x     = (const float*)d_in[0];
    const float* gamma = (const float*)d_in[1];
    const float* beta  = (const float*)d_in[2];
    const float* W_qkv = (const float*)d_in[3];
    const float* b_qkv = (const float*)d_in[4];
    const float* W_out = (const float*)d_in[5];
    const float* b_out = (const float*)d_in[6];
    float* out = (float*)d_out;
    char* ws = (char*)d_ws;

    __bf16* wqf   = (__bf16*)(ws + OFF_WQKV);
    __bf16* wof   = (__bf16*)(ws + OFF_WOUT);
    float2* stats = (float2*)(ws + OFF_STATS);
    __bf16* hid   = (__bf16*)(ws + OFF_HID);   // hid, then attn_out
    __bf16* qb    = (__bf16*)(ws + OFF_Q);
    __bf16* kb    = (__bf16*)(ws + OFF_K);
    __bf16* vbt   = (__bf16*)(ws + OFF_V);     // V^T kappa-ordered

    pre_kernel<<<1152, 256, 0, stream>>>(x, stats, W_qkv, W_out, wqf, wof);
    gn_apply<<<256, 256, 0, stream>>>(x, gamma, beta, stats, hid);
    qkv_gemm<<<dim3(256, 12), 256, 0, stream>>>(hid, wqf, b_qkv, qb, kb, vbt);
    attn_fwd<<<1024, 256, 0, stream>>>(qb, kb, vbt, hid);
    out_gemm<<<dim3(256, 4), 256, 0, stream>>>(hid, wof, b_out, x, out);
}

// Round 16
// 137.343 us; speedup vs baseline: 1.3948x; 1.3948x over previous
//
#include <hip/hip_runtime.h>
#include <math.h>

typedef float  f32x4  __attribute__((ext_vector_type(4)));
typedef __bf16 bf16x8 __attribute__((ext_vector_type(8)));
typedef __bf16 bf16x4 __attribute__((ext_vector_type(4)));

#define MFMA16(a, b, c) __builtin_amdgcn_mfma_f32_16x16x32_bf16((a), (b), (c), 0, 0, 0)

// tr-read: 64-bit LDS transpose read (4 bf16), literal offset
#define TRR(dst, a, lit)  asm volatile("ds_read_b64_tr_b16 %0, %1 offset:" lit : "=v"(dst) : "v"(a))
#define TRRM(dst, a, lit) asm volatile("ds_read_b64_tr_b16 %0, %1 offset:" lit : "=v"(dst) : "v"(a) : "memory")
#define SHUF8(a, b) __builtin_shufflevector((a), (b), 0, 1, 2, 3, 4, 5, 6, 7)

typedef __attribute__((address_space(3))) unsigned int lds_u32;
typedef __attribute__((address_space(1))) const unsigned int glb_u32;

__device__ __forceinline__ void gload16(const __bf16* g, char* l) {
    __builtin_amdgcn_global_load_lds((glb_u32*)g, (lds_u32*)l, 16, 0, 0);
}

// problem sizes
static constexpr int BATCH = 4;
static constexpr int CH    = 256;
static constexpr int M_TOT = BATCH * 4096;  // 16384

// qkv softmax pre-scale folded into Q: 0.125 * log2(e)
static constexpr float QSCALE = 0.18033688011112042f;

// workspace layout (bytes, 16-aligned)
static constexpr size_t OFF_WQKV  = 0;                              // 196608 bf16
static constexpr size_t OFF_WOUT  = 196608ull * 2;                  // 65536 bf16
static constexpr size_t OFF_STATS = OFF_WOUT + 65536ull * 2;        // 128 float2
static constexpr size_t OFF_HID   = OFF_STATS + 1024;               // hid / attn_out bf16
static constexpr size_t OFF_Q     = OFF_HID + (size_t)M_TOT * CH * 2;
static constexpr size_t OFF_K     = OFF_Q   + (size_t)M_TOT * CH * 2;
static constexpr size_t OFF_V     = OFF_K   + (size_t)M_TOT * CH * 2;

// ---------------------------------------------------------------------------
// 1) fused: GN stats (blocks 0..127) + weight convert/permute (blocks 128..1151)
// ---------------------------------------------------------------------------
__global__ __launch_bounds__(256) void pre_kernel(const float* __restrict__ x,
                                                  float2* __restrict__ stats,
                                                  const float* __restrict__ wq,
                                                  const float* __restrict__ wo,
                                                  __bf16* __restrict__ wqf,
                                                  __bf16* __restrict__ wof) {
    if (blockIdx.x < 128) {
        int bg = blockIdx.x;  // 0..127
        const float4* p = (const float4*)(x + (size_t)bg * 32768);
        float s = 0.f, ss = 0.f;
        for (int i = threadIdx.x; i < 8192; i += 256) {
            float4 v = p[i];
            s  += (v.x + v.y) + (v.z + v.w);
            ss += v.x * v.x + v.y * v.y + v.z * v.z + v.w * v.w;
        }
#pragma unroll
        for (int d = 32; d > 0; d >>= 1) { s += __shfl_down(s, d); ss += __shfl_down(ss, d); }
        __shared__ float sh[8];
        int w = threadIdx.x >> 6, l = threadIdx.x & 63;
        if (l == 0) { sh[w] = s; sh[4 + w] = ss; }
        __syncthreads();
        if (threadIdx.x == 0) {
            float S = sh[0] + sh[1] + sh[2] + sh[3];
            float SS = sh[4] + sh[5] + sh[6] + sh[7];
            float mean = S * (1.f / 32768.f);
            float var  = SS * (1.f / 32768.f) - mean * mean;
            stats[bg] = make_float2(mean, rsqrtf(var + 1e-5f));
        }
    } else {
        int i = (blockIdx.x - 128) * 256 + threadIdx.x;   // 0 .. 262143
        if (i < 196608) {
            int e = i & 7, l = (i >> 3) & 63, kk = (i >> 9) & 7, jt = i >> 12;  // jt 0..47
            int kidx = kk * 32 + ((l >> 4) << 3) + e;
            int n = jt * 16 + (l & 15);
            wqf[i] = (__bf16)wq[kidx * 768 + n];
        } else {
            int i2 = i - 196608;                  // 0 .. 65535
            int e = i2 & 7, l = (i2 >> 3) & 63, kk = (i2 >> 9) & 7, jt = i2 >> 12;  // jt 0..15
            int kidx = kk * 32 + ((l >> 4) << 3) + e;
            int n = jt * 16 + (l & 15);
            wof[i2] = (__bf16)wo[kidx * 256 + n];
        }
    }
}

// ---------------------------------------------------------------------------
// 2) GN apply + transpose: hid[b][n][c] = gn(x)[b][c][n]  (bf16)
// ---------------------------------------------------------------------------
__global__ __launch_bounds__(256) void gn_apply(const float* __restrict__ x,
                                                const float* __restrict__ gamma,
                                                const float* __restrict__ beta,
                                                const float2* __restrict__ stats,
                                                __bf16* __restrict__ hid) {
    int b  = blockIdx.x >> 6;
    int n0 = (blockIdx.x & 63) << 6;
    int c  = threadIdx.x;
    float2 st = stats[b * 32 + (c >> 3)];
    float gm = gamma[c] * st.y;
    float bt = beta[c] - st.x * gm;
    const float* xp = x + ((size_t)(b * 256 + c)) * 4096 + n0;
    __bf16* hp = hid + ((size_t)(b * 4096 + n0)) * 256 + c;
#pragma unroll
    for (int j4 = 0; j4 < 16; ++j4) {
        float4 v = *(const float4*)(xp + j4 * 4);
        hp[(size_t)(j4 * 4 + 0) * 256] = (__bf16)(v.x * gm + bt);
        hp[(size_t)(j4 * 4 + 1) * 256] = (__bf16)(v.y * gm + bt);
        hp[(size_t)(j4 * 4 + 2) * 256] = (__bf16)(v.z * gm + bt);
        hp[(size_t)(j4 * 4 + 3) * 256] = (__bf16)(v.w * gm + bt);
    }
}

// ---------------------------------------------------------------------------
// 3) QKV GEMM: [16384,256] x [256,768] + bias -> q/k/v [B,H,4096,64] bf16
//    Q pre-scaled by 0.125*log2(e).
// ---------------------------------------------------------------------------
__global__ __launch_bounds__(256) void qkv_gemm(const __bf16* __restrict__ hid,
                                                const __bf16* __restrict__ wf,
                                                const float* __restrict__ bqkv,
                                                __bf16* __restrict__ qb,
                                                __bf16* __restrict__ kb,
                                                __bf16* __restrict__ vb) {
    const int mt = blockIdx.x, nt = blockIdx.y;
    const int tid = threadIdx.x;
    const int w = tid >> 6, l = tid & 63;
    const int lr = l & 15, lh = l >> 4;
    f32x4 acc[4] = {{0.f,0.f,0.f,0.f},{0.f,0.f,0.f,0.f},{0.f,0.f,0.f,0.f},{0.f,0.f,0.f,0.f}};
    const __bf16* ap = hid + (size_t)(mt * 64 + w * 16 + lr) * 256 + lh * 8;
#pragma unroll
    for (int kk = 0; kk < 8; ++kk) {
        bf16x8 a = *(const bf16x8*)(ap + kk * 32);
#pragma unroll
        for (int fj = 0; fj < 4; ++fj) {
            bf16x8 bf = *(const bf16x8*)(wf + (size_t)(((nt * 4 + fj) * 8 + kk) * 64 + l) * 8);
            acc[fj] = MFMA16(a, bf, acc[fj]);
        }
    }
    int mbase = mt * 64 + w * 16 + lh * 4;
#pragma unroll
    for (int fj = 0; fj < 4; ++fj) {
        int j = nt * 64 + fj * 16 + lr;
        int head = j / 192, rem = j % 192;
        int part = rem >> 6, dd = rem & 63;
        float bias = bqkv[j];
        float sc = (part == 0) ? QSCALE : 1.0f;
        __bf16* dst = (part == 0) ? qb : (part == 1) ? kb : vb;
#pragma unroll
        for (int r = 0; r < 4; ++r) {
            int m = mbase + r;
            int b = m >> 12, n = m & 4095;
            dst[((size_t)((b * 4 + head) * 4096 + n)) * 64 + dd] = (__bf16)((acc[fj][r] + bias) * sc);
        }
    }
}

// ---------------------------------------------------------------------------
// 4) Flash attention, swapped-operand, STATIC softmax, x32 PV, 2 q-subtiles
//    per wave (128-row supertile). RING-4 tile slots + COUNTED vmcnt (T4):
//    body t reads slot t&3, stages tile t+2 into slot (t+2)&3 (4 gloads,
//    tail-clamped for uniform counting), ends with s_waitcnt vmcnt(4) +
//    raw s_barrier — no vmcnt(0) drain in the main loop.
//    Grid 512, XCD swizzle. LDS 64KB: K ring 4x8KB | V ring 4x8KB.
// ---------------------------------------------------------------------------
__global__ __launch_bounds__(256, 2) void attn_fwd(const __bf16* __restrict__ q,
                                                   const __bf16* __restrict__ k,
                                                   const __bf16* __restrict__ v,
                                                   __bf16* __restrict__ ao) {
    const int id = blockIdx.x;
    const int within = id >> 3;                       // 0..63
    const int bh = ((id & 7) << 1) + (within >> 5);   // XCD (id&7) owns bh pair
    const int q0 = (within & 31) * 128;
    const int tid = threadIdx.x;
    const int wv = tid >> 6, l = tid & 63;
    const int lr = l & 15, lh = l >> 4;

    __shared__ __attribute__((aligned(16))) char smem[65536];  // K[4][8K] | V[4][8K]

    const size_t base = (size_t)bh * (4096 * 64);

    // ---- staging addresses (chunk c = wv*64 + l, and +256) ----
    const int c0 = wv * 64 + l;
    const int rK = c0 >> 3, cbK = l & 7;
    const int gk0 = rK * 64 + (cbK ^ (rK & 7)) * 8;        // elements
    const int gk1 = gk0 + 2048;                             // +32 rows
    // V (pi-keyed layout): c -> dt=c>>7, kq=(c>>3)&15, klo=(l>>1)&3, d8=l&1
    const int dt0 = c0 >> 7, kq0 = (c0 >> 3) & 15, klo0 = (l >> 1) & 3, d80 = l & 1;
    const int gv0 = (kq0 * 4 + klo0) * 64 + dt0 * 16 + d80 * 8;
    const int gv1 = gv0 + 32;                               // dt+2
    const int lw0 = wv * 1024;                              // wave-uniform LDS bases
    const int lw1 = 4096 + wv * 1024;

    const __bf16* kg = k + base;
    const __bf16* vg = v + base;

    // per-lane tr-read base for V slot 0
    const unsigned lanep = (unsigned)(lr * 2 + lh * 128);
    const unsigned vAbase = (unsigned)(size_t)(smem + 32768) + lanep;

    // Q fragments for both subtiles (B-operand of swapped QK^T; pre-scaled)
    bf16x8 qf0a, qf1a, qf0b, qf1b;
    {
        const __bf16* qp = q + base + (size_t)(q0 + wv * 16 + lr) * 64 + lh * 8;
        qf0a = *(const bf16x8*)qp;
        qf1a = *(const bf16x8*)(qp + 32);
        qf0b = *(const bf16x8*)(qp + 4096);        // +64 rows
        qf1b = *(const bf16x8*)(qp + 4096 + 32);
    }
    bf16x8 ones;
#pragma unroll
    for (int e = 0; e < 8; ++e) ones[e] = (__bf16)1.0f;

    f32x4 oa[4] = {{0.f,0.f,0.f,0.f},{0.f,0.f,0.f,0.f},{0.f,0.f,0.f,0.f},{0.f,0.f,0.f,0.f}};
    f32x4 ob[4] = {{0.f,0.f,0.f,0.f},{0.f,0.f,0.f,0.f},{0.f,0.f,0.f,0.f},{0.f,0.f,0.f,0.f}};
    f32x4 o4a = {0.f, 0.f, 0.f, 0.f};
    f32x4 o4b = {0.f, 0.f, 0.f, 0.f};

    // prologue: stage tile 0 into slot 0, tile 1 into slot 1 (order matters)
#pragma unroll
    for (int s = 0; s < 2; ++s) {
        gload16(kg + s * 4096 + gk0, smem + s * 8192 + lw0);
        gload16(kg + s * 4096 + gk1, smem + s * 8192 + lw1);
        gload16(vg + s * 4096 + gv0, smem + 32768 + s * 8192 + lw0);
        gload16(vg + s * 4096 + gv1, smem + 32768 + s * 8192 + lw1);
    }
    asm volatile("s_waitcnt vmcnt(4)" ::: "memory");   // tile0's 4 loads done
    __builtin_amdgcn_s_barrier();

    auto body = [&](int slot, int tstage) {
        // stage tile (t+2) into slot (slot+2)&3 — always 4 loads (tail clamped)
        {
            int ts = (tstage <= 63) ? tstage : 62;
            const __bf16* kp = kg + (size_t)ts * 4096;
            const __bf16* vp = vg + (size_t)ts * 4096;
            char* kd = smem + ((slot + 2) & 3) * 8192;
            char* vd = smem + 32768 + ((slot + 2) & 3) * 8192;
            gload16(kp + gk0, kd + lw0);
            gload16(kp + gk1, kd + lw1);
            gload16(vp + gv0, vd + lw0);
            gload16(vp + gv1, vd + lw1);
        }
        const char* Kc = smem + slot * 8192;
        const unsigned vA = vAbase + (unsigned)(slot * 8192);

        // ---- S^T = K Q^T for both q-subtiles (K frags shared) ----
        f32x4 sa[4], sb[4];
        const f32x4 z = {0.f, 0.f, 0.f, 0.f};
        __builtin_amdgcn_s_setprio(1);
#pragma unroll
        for (int fj = 0; fj < 4; ++fj) {
            int row = fj * 16 + lr;
            bf16x8 kb0 = *(const bf16x8*)(Kc + row * 128 + ((lh * 16) ^ ((row & 7) << 4)));
            bf16x8 kb1 = *(const bf16x8*)(Kc + row * 128 + (((4 + lh) * 16) ^ ((row & 7) << 4)));
            sa[fj] = MFMA16(kb0, qf0a, z);
            sb[fj] = MFMA16(kb0, qf0b, z);
            sa[fj] = MFMA16(kb1, qf1a, sa[fj]);
            sb[fj] = MFMA16(kb1, qf1b, sb[fj]);
        }
        __builtin_amdgcn_s_setprio(0);

        // ---- issue ALL 16 V tr-reads; latency hides under exp2 ----
        bf16x4 u0, u1, u2, u3, u4, u5, u6, u7, u8, u9, u10, u11, u12, u13, u14, u15;
        TRRM(u0,  vA, "0");    TRR(u1,  vA, "512");
        TRR(u2,  vA, "1024");  TRR(u3,  vA, "1536");
        TRR(u4,  vA, "2048");  TRR(u5,  vA, "2560");
        TRR(u6,  vA, "3072");  TRR(u7,  vA, "3584");
        TRR(u8,  vA, "4096");  TRR(u9,  vA, "4608");
        TRR(u10, vA, "5120");  TRR(u11, vA, "5632");
        TRR(u12, vA, "6144");  TRR(u13, vA, "6656");
        TRR(u14, vA, "7168");  TRR(u15, vA, "7680");

        // ---- static softmax: p = exp2(s) -> PV B-fragments (in register) ----
        bf16x8 Ba0, Ba1, Bb0, Bb1;
#pragma unroll
        for (int fj = 0; fj < 4; ++fj)
#pragma unroll
            for (int r = 0; r < 4; ++r) {
                float pa = __builtin_amdgcn_exp2f(sa[fj][r]);
                float pb = __builtin_amdgcn_exp2f(sb[fj][r]);
                if (fj < 2) { Ba0[fj * 4 + r] = (__bf16)pa; Bb0[fj * 4 + r] = (__bf16)pb; }
                else        { Ba1[(fj - 2) * 4 + r] = (__bf16)pa; Bb1[(fj - 2) * 4 + r] = (__bf16)pb; }
            }

        // ---- single wait + one 20-MFMA cluster (V frags shared) ----
        asm volatile("s_waitcnt lgkmcnt(0)" ::: "memory");
        __builtin_amdgcn_sched_barrier(0);
        __builtin_amdgcn_s_setprio(1);
        bf16x8 v01 = SHUF8(u0,  u1),  v23 = SHUF8(u2,  u3);
        bf16x8 v45 = SHUF8(u4,  u5),  v67 = SHUF8(u6,  u7);
        oa[0] = MFMA16(v01, Ba0, oa[0]);  ob[0] = MFMA16(v01, Bb0, ob[0]);
        oa[1] = MFMA16(v45, Ba0, oa[1]);  ob[1] = MFMA16(v45, Bb0, ob[1]);
        oa[0] = MFMA16(v23, Ba1, oa[0]);  ob[0] = MFMA16(v23, Bb1, ob[0]);
        oa[1] = MFMA16(v67, Ba1, oa[1]);  ob[1] = MFMA16(v67, Bb1, ob[1]);
        o4a   = MFMA16(ones, Ba0, o4a);   o4b   = MFMA16(ones, Bb0, o4b);
        bf16x8 v89 = SHUF8(u8,  u9),  vab = SHUF8(u10, u11);
        bf16x8 vcd = SHUF8(u12, u13), vef = SHUF8(u14, u15);
        oa[2] = MFMA16(v89, Ba0, oa[2]);  ob[2] = MFMA16(v89, Bb0, ob[2]);
        oa[3] = MFMA16(vcd, Ba0, oa[3]);  ob[3] = MFMA16(vcd, Bb0, ob[3]);
        oa[2] = MFMA16(vab, Ba1, oa[2]);  ob[2] = MFMA16(vab, Bb1, ob[2]);
        oa[3] = MFMA16(vef, Ba1, oa[3]);  ob[3] = MFMA16(vef, Bb1, ob[3]);
        o4a   = MFMA16(ones, Ba1, o4a);   o4b   = MFMA16(ones, Bb1, o4b);
        __builtin_amdgcn_s_setprio(0);

        // counted barrier: leave THIS body's 4 loads in flight (no drain)
        asm volatile("s_waitcnt vmcnt(4)" ::: "memory");
        __builtin_amdgcn_s_barrier();
    };

    for (int t = 0; t < 64; t += 4) {
        body(0, t + 2);
        body(1, t + 3);
        body(2, t + 4);
        body(3, t + 5);
    }

    // epilogue: every lane holds the full denominators in o4a[0]/o4b[0]
    float inva = 1.0f / o4a[0];
    float invb = 1.0f / o4b[0];
    int b = bh >> 2, h = bh & 3;
    int n = q0 + wv * 16 + lr;
    __bf16* dsta = ao + ((size_t)(b * 4096 + n)) * 256 + h * 64 + lh * 4;
    __bf16* dstb = dsta + 64 * 256;
#pragma unroll
    for (int fd = 0; fd < 4; ++fd) {
        bf16x4 pka, pkb;
#pragma unroll
        for (int r = 0; r < 4; ++r) {
            pka[r] = (__bf16)(oa[fd][r] * inva);
            pkb[r] = (__bf16)(ob[fd][r] * invb);
        }
        *(bf16x4*)(dsta + fd * 16) = pka;
        *(bf16x4*)(dstb + fd * 16) = pkb;
    }
}

// ---------------------------------------------------------------------------
// 5) out projection + bias + residual + 1/sqrt(2), transposed store [B,C,N]
// ---------------------------------------------------------------------------
__global__ __launch_bounds__(256) void out_gemm(const __bf16* __restrict__ ao,
                                                const __bf16* __restrict__ wf,
                                                const float* __restrict__ bout,
                                                const float* __restrict__ x,
                                                float* __restrict__ out) {
    const int mt = blockIdx.x, nt = blockIdx.y;
    const int tid = threadIdx.x;
    const int w = tid >> 6, l = tid & 63;
    const int lr = l & 15, lh = l >> 4;
    f32x4 acc[4] = {{0.f,0.f,0.f,0.f},{0.f,0.f,0.f,0.f},{0.f,0.f,0.f,0.f},{0.f,0.f,0.f,0.f}};
    const __bf16* ap = ao + (size_t)(mt * 64 + w * 16 + lr) * 256 + lh * 8;
#pragma unroll
    for (int kk = 0; kk < 8; ++kk) {
        bf16x8 a = *(const bf16x8*)(ap + kk * 32);
#pragma unroll
        for (int fj = 0; fj < 4; ++fj) {
            bf16x8 bf = *(const bf16x8*)(wf + (size_t)(((nt * 4 + fj) * 8 + kk) * 64 + l) * 8);
            acc[fj] = MFMA16(a, bf, acc[fj]);
        }
    }
    __shared__ float tile[64][72];
#pragma unroll
    for (int fj = 0; fj < 4; ++fj) {
        float bias = bout[nt * 64 + fj * 16 + lr];
#pragma unroll
        for (int r = 0; r < 4; ++r)
            tile[w * 16 + lh * 4 + r][fj * 16 + lr] = acc[fj][r] + bias;
    }
    __syncthreads();
    int b  = mt >> 6;
    int n0 = (mt & 63) * 64;
    int c0 = nt * 64;
    int cl = tid >> 2, nq = tid & 3;
    size_t gbase = ((size_t)(b * 256 + c0 + cl)) * 4096 + n0 + nq * 16;
#pragma unroll
    for (int i = 0; i < 16; i += 4) {
        float4 xv = *(const float4*)(x + gbase + i);
        float4 ov;
        ov.x = (tile[nq * 16 + i + 0][cl] + xv.x) * 0.70710678118654752f;
        ov.y = (tile[nq * 16 + i + 1][cl] + xv.y) * 0.70710678118654752f;
        ov.z = (tile[nq * 16 + i + 2][cl] + xv.z) * 0.70710678118654752f;
        ov.w = (tile[nq * 16 + i + 3][cl] + xv.w) * 0.70710678118654752f;
        *(float4*)(out + gbase + i) = ov;
    }
}

// ---------------------------------------------------------------------------
extern "C" void kernel_launch(void* const* d_in, const int* in_sizes, int n_in,
                              void* d_out, int out_size, void* d_ws, size_t ws_size,
                              hipStream_t stream) {
    const float* x     = (const float*)d_in[0];
    const float* gamma = (const float*)d_in[1];
    const float* beta  = (const float*)d_in[2];
    const float* W_qkv = (const float*)d_in[3];
    const float* b_qkv = (const float*)d_in[4];
    const float* W_out = (const float*)d_in[5];
    const float* b_out = (const float*)d_in[6];
    float* out = (float*)d_out;
    char* ws = (char*)d_ws;

    __bf16* wqf   = (__bf16*)(ws + OFF_WQKV);
    __bf16* wof   = (__bf16*)(ws + OFF_WOUT);
    float2* stats = (float2*)(ws + OFF_STATS);
    __bf16* hid   = (__bf16*)(ws + OFF_HID);   // hid, then attn_out
    __bf16* qb    = (__bf16*)(ws + OFF_Q);
    __bf16* kb    = (__bf16*)(ws + OFF_K);
    __bf16* vb    = (__bf16*)(ws + OFF_V);

    pre_kernel<<<1152, 256, 0, stream>>>(x, stats, W_qkv, W_out, wqf, wof);
    gn_apply<<<256, 256, 0, stream>>>(x, gamma, beta, stats, hid);
    qkv_gemm<<<dim3(256, 12), 256, 0, stream>>>(hid, wqf, b_qkv, qb, kb, vb);
    attn_fwd<<<512, 256, 0, stream>>>(qb, kb, vb, hid);
    out_gemm<<<dim3(256, 4), 256, 0, stream>>>(hid, wof, b_out, x, out);
}